// Round 3
// baseline (343.017 us; speedup 1.0000x reference)
//
#include <hip/hip_runtime.h>
#include <hip/hip_bf16.h>

// MoE ExpertGroup: T=2048, E=8, D=1024, I=2048. fp32 in/out, bf16 MFMA compute.
// r3: wide k-major B staging + ds_read_b64_tr_b16 fragments, x pre-converted
// to bf16 (A side = pure global_load_lds w/ pre-swizzled source), BM=128.

#define T_ 2048
#define E_ 8
#define D_ 1024
#define I_ 2048
#define BM 128
#define BN 64
#define BK 64
#define MAXRT ((T_ / BM) + E_)  // 24 worst-case row tiles

typedef __attribute__((ext_vector_type(8))) __bf16 bf16x8;
typedef __attribute__((ext_vector_type(4))) __bf16 bf16x4;
typedef __attribute__((ext_vector_type(4))) float f32x4;
typedef __attribute__((ext_vector_type(4))) unsigned short us4;
typedef __attribute__((ext_vector_type(8))) unsigned short us8;

__device__ __forceinline__ unsigned short b16(float f) {
  __hip_bfloat16 h = __float2bfloat16(f);  // RNE
  return *reinterpret_cast<unsigned short*>(&h);
}

__device__ __forceinline__ void gload16(const void* g, unsigned lds_addr) {
  __builtin_amdgcn_global_load_lds(
      (const __attribute__((address_space(1))) unsigned int*)(unsigned long long)g,
      (__attribute__((address_space(3))) unsigned int*)(unsigned long long)lds_addr,
      16, 0, 0);
}

// ---------------- kernel 0: x fp32 -> bf16 ----------------
__global__ __launch_bounds__(256) void x_to_bf16(const float* __restrict__ x,
                                                 __hip_bfloat16* __restrict__ xb) {
  const int idx = blockIdx.x * 256 + threadIdx.x;  // 8 floats per thread
  const float4* px = (const float4*)x;
  const float4 a = px[idx * 2], b = px[idx * 2 + 1];
  us8 v = {b16(a.x), b16(a.y), b16(a.z), b16(a.w), b16(b.x), b16(b.y), b16(b.z), b16(b.w)};
  *(us8*)(xb + (size_t)idx * 8) = v;
}

// ---------------- kernel 1: count + permute ----------------
// meta (ints): [0..7] counts, [8..15] segment starts, [16..16+T) perm
__global__ void moe_count(const int* __restrict__ eidx, int* __restrict__ meta) {
  __shared__ int cnt[E_], cur[E_];
  const int tid = threadIdx.x;
  if (tid < E_) cnt[tid] = 0;
  __syncthreads();
  for (int t = tid; t < T_; t += 256) atomicAdd(&cnt[eidx[t]], 1);
  __syncthreads();
  if (tid == 0) {
    int s = 0;
    for (int i = 0; i < E_; ++i) {
      int c = cnt[i];
      meta[i] = c;
      meta[8 + i] = s;
      cur[i] = s;
      s += c;
    }
  }
  __syncthreads();
  for (int t = tid; t < T_; t += 256) {
    int e = eidx[t];
    int pp = atomicAdd(&cur[e], 1);
    meta[16 + pp] = t;
  }
}

__device__ __forceinline__ bool resolve_tile(const int* __restrict__ meta, int rt,
                                             int& e, int& row0, int& rows_valid) {
  int cum = 0;
  e = -1;
  row0 = 0;
  rows_valid = 0;
#pragma unroll
  for (int i = 0; i < E_; ++i) {
    int n = meta[i];
    int nt = (n + BM - 1) >> 7;
    if (e < 0 && rt < cum + nt) {
      e = i;
      int segS = meta[8 + i];
      row0 = segS + (rt - cum) * BM;
      int rv = segS + n - row0;
      rows_valid = rv > BM ? BM : rv;
    }
    cum += nt;
  }
  return e >= 0;
}

// LDS layouts per K-tile:
//  A [128 m][8 chunk]: chunk pcb holds k-block pcb^(m&7) (16B, 8 bf16) -> ds_read_b128
//  B [BK/4 kq][BN/16 ns][4][16] bf16 subtiles -> ds_read_b64_tr_b16:
//    group h, per-lane addr = kq(kk,h)*512 + wv*128 + (lane&15)*8 gives lane p
//    column n=wv*16+p, elems j -> k=kq*4+j ; two reads (offset:512) -> k 0..7.

// ---------------- kernel 2: gate/up GEMM + SiLU ----------------
__global__ __launch_bounds__(256) void moe_gemm1(
    const __hip_bfloat16* __restrict__ xb, const float* __restrict__ wg,
    const float* __restrict__ wu, const int* __restrict__ meta,
    __hip_bfloat16* __restrict__ hidden) {
  __shared__ char smem[2 * 32768];  // buf: A 16K @0, Bg 8K @16K, Bu 8K @24K
  const int tid = threadIdx.x;
  const int lane = tid & 63;
  const int wv = tid >> 6;
  const int p = lane & 15, h = lane >> 4;

  int e, row0, rows_valid;
  if (!resolve_tile(meta, blockIdx.x, e, row0, rows_valid)) return;
  const int ct = blockIdx.y;
  const int* __restrict__ perm = meta + 16;

  // A: 4 slots/thread via global_load_lds (linear dest, pre-swizzled source)
  const __hip_bfloat16* gA[4];
  unsigned lAdst[4];
#pragma unroll
  for (int q = 0; q < 4; ++q) {
    const int s = q * 256 + tid;
    const int m = s >> 3, pcb = s & 7;
    const int kblk = pcb ^ (m & 7);
    const int mm = m < rows_valid ? m : (rows_valid - 1);
    const int tok = perm[row0 + mm];
    gA[q] = xb + (size_t)tok * D_ + kblk * 8;
    lAdst[q] = (unsigned)(s * 16);
  }
  // B: 4 slots/thread/mat, wide float4 loads, k-major subtiled LDS
  const float* wgb = wg + (size_t)e * D_ * I_;
  const float* wub = wu + (size_t)e * D_ * I_;
  size_t gBoff[4];
  unsigned lB[4];
#pragma unroll
  for (int q = 0; q < 4; ++q) {
    const int s = q * 256 + tid;
    const int k = s >> 4, fq = s & 15;
    gBoff[q] = (size_t)k * I_ + (size_t)(ct * BN + fq * 4);
    lB[q] = (unsigned)((k >> 2) * 512 + (fq >> 2) * 128 + (k & 3) * 32 + (fq & 3) * 8);
  }
  unsigned offA[8][2];
#pragma unroll
  for (int mf = 0; mf < 8; ++mf)
#pragma unroll
    for (int kk = 0; kk < 2; ++kk)
      offA[mf][kk] = (unsigned)((mf * 16 + p) * 128 + (((kk * 4 + h) ^ (p & 7)) * 16));
  unsigned trb[2];
#pragma unroll
  for (int kk = 0; kk < 2; ++kk)
    trb[kk] = (unsigned)(kk * 4096 + h * 1024 + wv * 128 + p * 8);
  const unsigned ldsbase = (unsigned)(unsigned long long)smem;

  f32x4 accG[8], accU[8];
#pragma unroll
  for (int i = 0; i < 8; ++i) {
    accG[i] = f32x4{0.f, 0.f, 0.f, 0.f};
    accU[i] = f32x4{0.f, 0.f, 0.f, 0.f};
  }

  float4 rg[4], ru[4];
  auto LOADB = [&](int kt) {
#pragma unroll
    for (int q = 0; q < 4; ++q) {
      const size_t o = (size_t)kt * BK * I_ + gBoff[q];
      rg[q] = *(const float4*)(wgb + o);
      ru[q] = *(const float4*)(wub + o);
    }
  };
  auto WRITEB = [&](unsigned base) {
#pragma unroll
    for (int q = 0; q < 4; ++q) {
      us4 vg = {b16(rg[q].x), b16(rg[q].y), b16(rg[q].z), b16(rg[q].w)};
      us4 vu = {b16(ru[q].x), b16(ru[q].y), b16(ru[q].z), b16(ru[q].w)};
      *(us4*)(smem + base + 16384u + lB[q]) = vg;
      *(us4*)(smem + base + 24576u + lB[q]) = vu;
    }
  };
  auto GLOADA = [&](unsigned base, int kt) {
#pragma unroll
    for (int q = 0; q < 4; ++q) gload16(gA[q] + kt * BK, ldsbase + base + lAdst[q]);
  };
  auto COMPUTE = [&](unsigned cur) {
#pragma unroll
    for (int kk = 0; kk < 2; ++kk) {
      bf16x8 aF[8];
#pragma unroll
      for (int mf = 0; mf < 8; ++mf)
        aF[mf] = *(const bf16x8*)(smem + cur + offA[mf][kk]);
      const unsigned ag = ldsbase + cur + 16384u + trb[kk];
      const unsigned au = ldsbase + cur + 24576u + trb[kk];
      bf16x4 g0, g1, u0, u1;
      asm volatile("ds_read_b64_tr_b16 %0, %1" : "=v"(g0) : "v"(ag));
      asm volatile("ds_read_b64_tr_b16 %0, %1 offset:512" : "=v"(g1) : "v"(ag));
      asm volatile("ds_read_b64_tr_b16 %0, %1" : "=v"(u0) : "v"(au));
      asm volatile("ds_read_b64_tr_b16 %0, %1 offset:512" : "=v"(u1) : "v"(au));
      asm volatile("s_waitcnt lgkmcnt(0)" ::: "memory");
      __builtin_amdgcn_sched_barrier(0);
      const bf16x8 bg = __builtin_shufflevector(g0, g1, 0, 1, 2, 3, 4, 5, 6, 7);
      const bf16x8 bu = __builtin_shufflevector(u0, u1, 0, 1, 2, 3, 4, 5, 6, 7);
#pragma unroll
      for (int mf = 0; mf < 8; ++mf) {
        accG[mf] = __builtin_amdgcn_mfma_f32_16x16x32_bf16(aF[mf], bg, accG[mf], 0, 0, 0);
        accU[mf] = __builtin_amdgcn_mfma_f32_16x16x32_bf16(aF[mf], bu, accU[mf], 0, 0, 0);
      }
    }
  };

  GLOADA(0, 0);
  LOADB(0);
  WRITEB(0);
  __syncthreads();
  const int KT = D_ / BK;  // 16
  for (int kt = 0; kt < KT; ++kt) {
    const unsigned cur = (unsigned)(kt & 1) * 32768u;
    if (kt + 1 < KT) {
      GLOADA(cur ^ 32768u, kt + 1);
      LOADB(kt + 1);
    }
    COMPUTE(cur);
    if (kt + 1 < KT) WRITEB(cur ^ 32768u);
    __syncthreads();
  }

  // epilogue: C/D col=lane&15, row=(lane>>4)*4+j
  const int cbase = ct * BN + wv * 16 + p;
#pragma unroll
  for (int mf = 0; mf < 8; ++mf) {
#pragma unroll
    for (int j = 0; j < 4; ++j) {
      const int r = mf * 16 + h * 4 + j;
      if (r < rows_valid) {
        const float gv = accG[mf][j], uv = accU[mf][j];
        const float hv = gv / (1.f + __expf(-gv)) * uv;
        hidden[(size_t)(row0 + r) * I_ + cbase] = __float2bfloat16(hv);
      }
    }
  }
}

// ---------------- kernel 3: down GEMM + scatter ----------------
__global__ __launch_bounds__(256) void moe_gemm2(
    const __hip_bfloat16* __restrict__ hidden, const float* __restrict__ wd,
    const int* __restrict__ meta, float* __restrict__ out) {
  __shared__ char smem[2 * 24576];  // buf: A 16K @0, B 8K @16K
  const int tid = threadIdx.x;
  const int lane = tid & 63;
  const int wv = tid >> 6;
  const int p = lane & 15, h = lane >> 4;

  int e, row0, rows_valid;
  if (!resolve_tile(meta, blockIdx.x, e, row0, rows_valid)) return;
  const int ct = blockIdx.y;
  const int* __restrict__ perm = meta + 16;

  const __hip_bfloat16* gA[4];
  unsigned lAdst[4];
#pragma unroll
  for (int q = 0; q < 4; ++q) {
    const int s = q * 256 + tid;
    const int m = s >> 3, pcb = s & 7;
    const int kblk = pcb ^ (m & 7);
    const int mm = row0 + (m < rows_valid ? m : (rows_valid - 1));
    gA[q] = hidden + (size_t)mm * I_ + kblk * 8;
    lAdst[q] = (unsigned)(s * 16);
  }
  const float* wdb = wd + (size_t)e * I_ * D_;
  size_t gBoff[4];
  unsigned lB[4];
#pragma unroll
  for (int q = 0; q < 4; ++q) {
    const int s = q * 256 + tid;
    const int k = s >> 4, fq = s & 15;
    gBoff[q] = (size_t)k * D_ + (size_t)(ct * BN + fq * 4);
    lB[q] = (unsigned)((k >> 2) * 512 + (fq >> 2) * 128 + (k & 3) * 32 + (fq & 3) * 8);
  }
  unsigned offA[8][2];
#pragma unroll
  for (int mf = 0; mf < 8; ++mf)
#pragma unroll
    for (int kk = 0; kk < 2; ++kk)
      offA[mf][kk] = (unsigned)((mf * 16 + p) * 128 + (((kk * 4 + h) ^ (p & 7)) * 16));
  unsigned trb[2];
#pragma unroll
  for (int kk = 0; kk < 2; ++kk)
    trb[kk] = (unsigned)(kk * 4096 + h * 1024 + wv * 128 + p * 8);
  const unsigned ldsbase = (unsigned)(unsigned long long)smem;

  f32x4 acc[8];
#pragma unroll
  for (int i = 0; i < 8; ++i) acc[i] = f32x4{0.f, 0.f, 0.f, 0.f};

  float4 rd[4];
  auto LOADB = [&](int kt) {
#pragma unroll
    for (int q = 0; q < 4; ++q) rd[q] = *(const float4*)(wdb + (size_t)kt * BK * D_ + gBoff[q]);
  };
  auto WRITEB = [&](unsigned base) {
#pragma unroll
    for (int q = 0; q < 4; ++q) {
      us4 v = {b16(rd[q].x), b16(rd[q].y), b16(rd[q].z), b16(rd[q].w)};
      *(us4*)(smem + base + 16384u + lB[q]) = v;
    }
  };
  auto GLOADA = [&](unsigned base, int kt) {
#pragma unroll
    for (int q = 0; q < 4; ++q) gload16(gA[q] + kt * BK, ldsbase + base + lAdst[q]);
  };

  GLOADA(0, 0);
  LOADB(0);
  WRITEB(0);
  __syncthreads();
  const int KT = I_ / BK;  // 32
  for (int kt = 0; kt < KT; ++kt) {
    const unsigned cur = (unsigned)(kt & 1) * 24576u;
    if (kt + 1 < KT) {
      GLOADA(cur ^ 24576u, kt + 1);
      LOADB(kt + 1);
    }
#pragma unroll
    for (int kk = 0; kk < 2; ++kk) {
      bf16x8 aF[8];
#pragma unroll
      for (int mf = 0; mf < 8; ++mf)
        aF[mf] = *(const bf16x8*)(smem + cur + offA[mf][kk]);
      const unsigned ab = ldsbase + cur + 16384u + trb[kk];
      bf16x4 b0, b1;
      asm volatile("ds_read_b64_tr_b16 %0, %1" : "=v"(b0) : "v"(ab));
      asm volatile("ds_read_b64_tr_b16 %0, %1 offset:512" : "=v"(b1) : "v"(ab));
      asm volatile("s_waitcnt lgkmcnt(0)" ::: "memory");
      __builtin_amdgcn_sched_barrier(0);
      const bf16x8 bb = __builtin_shufflevector(b0, b1, 0, 1, 2, 3, 4, 5, 6, 7);
#pragma unroll
      for (int mf = 0; mf < 8; ++mf)
        acc[mf] = __builtin_amdgcn_mfma_f32_16x16x32_bf16(aF[mf], bb, acc[mf], 0, 0, 0);
    }
    if (kt + 1 < KT) WRITEB(cur ^ 24576u);
    __syncthreads();
  }

  const int cbase = ct * BN + wv * 16 + p;
#pragma unroll
  for (int mf = 0; mf < 8; ++mf) {
#pragma unroll
    for (int j = 0; j < 4; ++j) {
      const int r = mf * 16 + h * 4 + j;
      if (r < rows_valid) {
        const int tok = perm[row0 + r];
        out[(size_t)tok * D_ + cbase] = acc[mf][j];
      }
    }
  }
}

extern "C" void kernel_launch(void* const* d_in, const int* in_sizes, int n_in,
                              void* d_out, int out_size, void* d_ws, size_t ws_size,
                              hipStream_t stream) {
  const float* x = (const float*)d_in[0];
  const int* eidx = (const int*)d_in[1];
  const float* wgate = (const float*)d_in[2];
  const float* wup = (const float*)d_in[3];
  const float* wdown = (const float*)d_in[4];
  float* out = (float*)d_out;

  int* meta = (int*)d_ws;                                            // 8.3 KB
  __hip_bfloat16* xb = (__hip_bfloat16*)((char*)d_ws + 65536);       // 4 MB
  __hip_bfloat16* hidden = (__hip_bfloat16*)((char*)d_ws + 4259840); // 8 MB

  x_to_bf16<<<dim3((T_ * D_) / (256 * 8)), dim3(256), 0, stream>>>(x, xb);
  moe_count<<<dim3(1), dim3(256), 0, stream>>>(eidx, meta);
  moe_gemm1<<<dim3(MAXRT, I_ / BN), dim3(256), 0, stream>>>(xb, wgate, wup, meta, hidden);
  moe_gemm2<<<dim3(MAXRT, D_ / BN), dim3(256), 0, stream>>>(hidden, wdown, meta, out);
}